// Round 1
// baseline (705.126 us; speedup 1.0000x reference)
//
#include <hip/hip_runtime.h>

// ---------------------------------------------------------------------------
// relu linear attention, fp32 baseline
//   q,k,v: [B=4][H=8][d=128][N=8192] fp32  (n contiguous)
//   out:   [B][d][H][N] fp32 (from transpose(0,2,1,3).reshape(B,-1,1024))
//
//   pass1: partial_vk[bh][split][d(129)][e(128)] = sum_n v_pad[d][n]*relu(k[e][n])
//   pass2: reduce partials -> vk[bh][129][128]
//   pass3: out[d][n] = (sum_e vk[d][e]*relu(q[e][n])) / (sum_e vk[128][e]*relu(q[e][n]))
// ---------------------------------------------------------------------------

#define TS 32      // n-tile staged in LDS per iteration (pass 1)
#define LSTR 36    // LDS row stride (32 + 4 pad): float4-aligned, 2-way-max banks
#define QSTR 132   // vkT LDS row stride (129 rounded up, float4-aligned)

__global__ __launch_bounds__(256) void p1_vk_partial(
    const float* __restrict__ K, const float* __restrict__ V,
    float* __restrict__ partial, int nsplit, int chunk)
{
    __shared__ float sk[128 * LSTR];
    __shared__ float sv[128 * LSTR];
    const int bh    = blockIdx.y;
    const int split = blockIdx.x;
    const int tid   = threadIdx.x;
    const int tr    = tid >> 4;   // 0..15  (v-row group)
    const int tc    = tid & 15;   // 0..15  (k-row group)
    const size_t base = (size_t)bh * (128 * 8192);
    const int n0 = split * chunk;

    float acc[8][8];
#pragma unroll
    for (int i = 0; i < 8; ++i)
#pragma unroll
        for (int j = 0; j < 8; ++j) acc[i][j] = 0.f;
    float ksum[8] = {0.f, 0.f, 0.f, 0.f, 0.f, 0.f, 0.f, 0.f};

    for (int nt = n0; nt < n0 + chunk; nt += TS) {
        // stage 128 rows x 32 n of k (relu'd) and v into LDS
#pragma unroll
        for (int l = 0; l < 4; ++l) {
            const int idx = tid + l * 256;      // 0..1023
            const int row = idx >> 3;           // 0..127
            const int col = (idx & 7) << 2;     // 0,4,...,28
            const float4 kv = *(const float4*)(K + base + (size_t)row * 8192 + nt + col);
            const float4 vv = *(const float4*)(V + base + (size_t)row * 8192 + nt + col);
            float4 kr;
            kr.x = fmaxf(kv.x, 0.f); kr.y = fmaxf(kv.y, 0.f);
            kr.z = fmaxf(kv.z, 0.f); kr.w = fmaxf(kv.w, 0.f);
            *(float4*)(sk + row * LSTR + col) = kr;
            *(float4*)(sv + row * LSTR + col) = vv;
        }
        __syncthreads();

#pragma unroll
        for (int n = 0; n < TS; n += 4) {
            float4 a[8], b[8];
#pragma unroll
            for (int i = 0; i < 8; ++i) a[i] = *(const float4*)(sv + (tr + 16 * i) * LSTR + n);
#pragma unroll
            for (int j = 0; j < 8; ++j) b[j] = *(const float4*)(sk + (tc + 16 * j) * LSTR + n);
#pragma unroll
            for (int i = 0; i < 8; ++i)
#pragma unroll
                for (int j = 0; j < 8; ++j) {
                    acc[i][j] = fmaf(a[i].x, b[j].x, acc[i][j]);
                    acc[i][j] = fmaf(a[i].y, b[j].y, acc[i][j]);
                    acc[i][j] = fmaf(a[i].z, b[j].z, acc[i][j]);
                    acc[i][j] = fmaf(a[i].w, b[j].w, acc[i][j]);
                }
            if (tr == 0) {  // ones-row: column sums of relu(k)
#pragma unroll
                for (int j = 0; j < 8; ++j)
                    ksum[j] += (b[j].x + b[j].y) + (b[j].z + b[j].w);
            }
        }
        __syncthreads();
    }

    float* p = partial + (size_t)(bh * nsplit + split) * (129 * 128);
#pragma unroll
    for (int i = 0; i < 8; ++i)
#pragma unroll
        for (int j = 0; j < 8; ++j)
            p[(tr + 16 * i) * 128 + (tc + 16 * j)] = acc[i][j];
    if (tr == 0) {
#pragma unroll
        for (int j = 0; j < 8; ++j)
            p[128 * 128 + tc + 16 * j] = ksum[j];
    }
}

__global__ __launch_bounds__(256) void p2_vk_reduce(
    const float* __restrict__ partial, float* __restrict__ vk, int nsplit)
{
    const int t = blockIdx.x * 256 + threadIdx.x;
    if (t >= 32 * 129 * 128) return;
    const int bh = t / (129 * 128);
    const int rc = t % (129 * 128);
    float s = 0.f;
    for (int i = 0; i < nsplit; ++i)
        s += partial[(size_t)(bh * nsplit + i) * (129 * 128) + rc];
    vk[t] = s;
}

__global__ __launch_bounds__(256) void p3_out(
    const float* __restrict__ Q, const float* __restrict__ vk,
    float* __restrict__ out)
{
    extern __shared__ float svkT[];       // [128 e][QSTR] ; col d = 0..128 (128 = ones row)
    const int bh  = blockIdx.y;
    const int b   = bh >> 3, h = bh & 7;
    const int nbase = blockIdx.x * 128;
    const int tid = threadIdx.x;
    const int tr  = tid >> 4, tc = tid & 15;

    const float* vkp = vk + (size_t)bh * (129 * 128);
    for (int idx = tid; idx < 129 * 128; idx += 256) {
        const int d = idx >> 7;   // 0..128
        const int e = idx & 127;
        svkT[e * QSTR + d] = vkp[idx];
    }
    __syncthreads();

    const float* qp = Q + (size_t)bh * (128 * 8192) + nbase + tc * 8;

    float acc[8][8];
#pragma unroll
    for (int i = 0; i < 8; ++i)
#pragma unroll
        for (int j = 0; j < 8; ++j) acc[i][j] = 0.f;
    float den[8] = {0.f, 0.f, 0.f, 0.f, 0.f, 0.f, 0.f, 0.f};

#pragma unroll 4
    for (int e = 0; e < 128; ++e) {
        const float4 q0 = *(const float4*)(qp + (size_t)e * 8192);
        const float4 q1 = *(const float4*)(qp + (size_t)e * 8192 + 4);
        float bb[8];
        bb[0] = fmaxf(q0.x, 0.f); bb[1] = fmaxf(q0.y, 0.f);
        bb[2] = fmaxf(q0.z, 0.f); bb[3] = fmaxf(q0.w, 0.f);
        bb[4] = fmaxf(q1.x, 0.f); bb[5] = fmaxf(q1.y, 0.f);
        bb[6] = fmaxf(q1.z, 0.f); bb[7] = fmaxf(q1.w, 0.f);
        float a[8];
#pragma unroll
        for (int i = 0; i < 8; ++i) a[i] = svkT[e * QSTR + tr + 16 * i];
        const float w = svkT[e * QSTR + 128];
#pragma unroll
        for (int i = 0; i < 8; ++i)
#pragma unroll
            for (int j = 0; j < 8; ++j)
                acc[i][j] = fmaf(a[i], bb[j], acc[i][j]);
#pragma unroll
        for (int j = 0; j < 8; ++j) den[j] = fmaf(w, bb[j], den[j]);
    }

    float rden[8];
#pragma unroll
    for (int j = 0; j < 8; ++j) rden[j] = 1.f / den[j];

#pragma unroll
    for (int i = 0; i < 8; ++i) {
        const int d = tr + 16 * i;
        float* op = out + (((size_t)b * 128 + d) * 8 + h) * 8192 + nbase + tc * 8;
        float4 o0, o1;
        o0.x = acc[i][0] * rden[0]; o0.y = acc[i][1] * rden[1];
        o0.z = acc[i][2] * rden[2]; o0.w = acc[i][3] * rden[3];
        o1.x = acc[i][4] * rden[4]; o1.y = acc[i][5] * rden[5];
        o1.z = acc[i][6] * rden[6]; o1.w = acc[i][7] * rden[7];
        *(float4*)op = o0;
        *(float4*)(op + 4) = o1;
    }
}

extern "C" void kernel_launch(void* const* d_in, const int* in_sizes, int n_in,
                              void* d_out, int out_size, void* d_ws, size_t ws_size,
                              hipStream_t stream)
{
    const float* q = (const float*)d_in[0];
    const float* k = (const float*)d_in[1];
    const float* v = (const float*)d_in[2];
    float* out = (float*)d_out;
    float* ws  = (float*)d_ws;

    const size_t vk_elems = 32ull * 129 * 128;   // 528384 floats = 2.11 MB

    // pick nsplit so that (nsplit+1) * vk bytes fit in workspace
    int nsplit = 16;
    while (nsplit > 1 && (vk_elems * (size_t)(nsplit + 1)) * 4 > ws_size) nsplit >>= 1;
    const int chunk = 8192 / nsplit;

    float* partial = ws;
    float* vkbuf   = ws + vk_elems * (size_t)nsplit;

    dim3 g1(nsplit, 32);
    p1_vk_partial<<<g1, 256, 0, stream>>>(k, v, partial, nsplit, chunk);

    const int redn = (int)((vk_elems + 255) / 256);
    p2_vk_reduce<<<redn, 256, 0, stream>>>(partial, vkbuf, nsplit);

    dim3 g3(64, 32);
    p3_out<<<g3, 256, 67584 /* 128*132*4 dynamic LDS */, stream>>>(q, vkbuf, out);
}

// Round 2
// 325.933 us; speedup vs baseline: 2.1634x; 2.1634x over previous
//
#include <hip/hip_runtime.h>

// ---------------------------------------------------------------------------
// relu linear attention, fp32 (de-spilled)
//   q,k,v: [B=4][H=8][d=128][N=8192] fp32  (n contiguous)
//   out:   [B][d][H][N] fp32
//
//   pass1: partial_vk[bh][split][d(129)][e(128)] = sum_n v_pad[d][n]*relu(k[e][n])
//   pass2: reduce partials -> vk[bh][129][128]
//   pass3: out[d][n] = (sum_e vk[d][e]*relu(q[e][n])) / (sum_e vk[128][e]*relu(q[e][n]))
// ---------------------------------------------------------------------------

#define TS 32      // n-tile staged in LDS per iteration (pass 1)
#define LSTR 36    // LDS row stride (32 + 4 pad)
#define QSTR 132   // vkT LDS row stride (129 rounded up, float4-aligned)

__global__ __launch_bounds__(256, 3) void p1_vk_partial(
    const float* __restrict__ K, const float* __restrict__ V,
    float* __restrict__ partial, int nsplit, int chunk)
{
    __shared__ float sk[128 * LSTR];
    __shared__ float sv[128 * LSTR];
    const int bh    = blockIdx.y;
    const int split = blockIdx.x;
    const int tid   = threadIdx.x;
    const int tr    = tid >> 4;   // 0..15  (v-row group)
    const int tc    = tid & 15;   // 0..15  (k-row group)
    const int r0    = tid >> 3;   // 0..31  (staging row group)
    const int c8    = tid & 7;    // staging col-block
    const size_t base = (size_t)bh * (128 * 8192);
    const int n0 = split * chunk;

    float acc[8][8];
#pragma unroll
    for (int i = 0; i < 8; ++i)
#pragma unroll
        for (int j = 0; j < 8; ++j) acc[i][j] = 0.f;
    float kpart[4] = {0.f, 0.f, 0.f, 0.f};   // relu(k) row-sums, gathered in staging

    for (int nt = n0; nt < n0 + chunk; nt += TS) {
        // stage 128 rows x 32 n of relu(k) and v into LDS; fold ksum into staging
#pragma unroll
        for (int l = 0; l < 4; ++l) {
            const int row = r0 + 32 * l;
            const int col = c8 << 2;
            const float4 kv = *(const float4*)(K + base + (size_t)row * 8192 + nt + col);
            const float4 vv = *(const float4*)(V + base + (size_t)row * 8192 + nt + col);
            float4 kr;
            kr.x = fmaxf(kv.x, 0.f); kr.y = fmaxf(kv.y, 0.f);
            kr.z = fmaxf(kv.z, 0.f); kr.w = fmaxf(kv.w, 0.f);
            kpart[l] += (kr.x + kr.y) + (kr.z + kr.w);
            *(float4*)(sk + row * LSTR + col) = kr;
            *(float4*)(sv + row * LSTR + col) = vv;
        }
        __syncthreads();

#pragma unroll 1
        for (int n = 0; n < TS; n += 4) {
            float4 a[8];
#pragma unroll
            for (int i = 0; i < 8; ++i)
                a[i] = *(const float4*)(sv + (tr + 16 * i) * LSTR + n);
#pragma unroll
            for (int j = 0; j < 8; ++j) {
                const float4 b = *(const float4*)(sk + (tc + 16 * j) * LSTR + n);
#pragma unroll
                for (int i = 0; i < 8; ++i) {
                    acc[i][j] = fmaf(a[i].x, b.x, acc[i][j]);
                    acc[i][j] = fmaf(a[i].y, b.y, acc[i][j]);
                    acc[i][j] = fmaf(a[i].z, b.z, acc[i][j]);
                    acc[i][j] = fmaf(a[i].w, b.w, acc[i][j]);
                }
            }
        }
        __syncthreads();
    }

    // reduce kpart (8 col-partials per row) through LDS (sk is dead now)
#pragma unroll
    for (int l = 0; l < 4; ++l)
        sk[(r0 + 32 * l) * 8 + c8] = kpart[l];
    __syncthreads();

    float* p = partial + (size_t)(bh * nsplit + split) * (129 * 128);
#pragma unroll
    for (int i = 0; i < 8; ++i)
#pragma unroll
        for (int j = 0; j < 8; ++j)
            p[(tr + 16 * i) * 128 + (tc + 16 * j)] = acc[i][j];
    if (tid < 128) {
        float s = 0.f;
#pragma unroll
        for (int j = 0; j < 8; ++j) s += sk[tid * 8 + j];
        p[128 * 128 + tid] = s;
    }
}

__global__ __launch_bounds__(256) void p2_vk_reduce(
    const float* __restrict__ partial, float* __restrict__ vk, int nsplit)
{
    const int t = blockIdx.x * 256 + threadIdx.x;
    if (t >= 32 * 129 * 128) return;
    const int bh = t / (129 * 128);
    const int rc = t % (129 * 128);
    float s = 0.f;
    for (int i = 0; i < nsplit; ++i)
        s += partial[(size_t)(bh * nsplit + i) * (129 * 128) + rc];
    vk[t] = s;
}

__global__ __launch_bounds__(512, 4) void p3_out(
    const float* __restrict__ Q, const float* __restrict__ vk,
    float* __restrict__ out)
{
    extern __shared__ float svkT[];       // [128 e][QSTR]; col d = 0..128 (128 = ones row)
    const int bh  = blockIdx.y;
    const int b   = bh >> 3, h = bh & 7;
    const int nbase = blockIdx.x * 256;
    const int tid = threadIdx.x;
    const int tr  = tid >> 5;   // 0..15
    const int tc  = tid & 31;   // 0..31

    const float* vkp = vk + (size_t)bh * (129 * 128);
    for (int idx = tid; idx < 129 * 128; idx += 512) {
        const int d = idx >> 7;   // 0..128
        const int e = idx & 127;
        svkT[e * QSTR + d] = vkp[idx];
    }
    __syncthreads();

    const float* qp = Q + (size_t)bh * (128 * 8192) + nbase + tc * 8;

    float acc[8][8];
#pragma unroll
    for (int i = 0; i < 8; ++i)
#pragma unroll
        for (int j = 0; j < 8; ++j) acc[i][j] = 0.f;
    float den[8] = {0.f, 0.f, 0.f, 0.f, 0.f, 0.f, 0.f, 0.f};

#pragma unroll 2
    for (int e = 0; e < 128; ++e) {
        const float4 q0 = *(const float4*)(qp + (size_t)e * 8192);
        const float4 q1 = *(const float4*)(qp + (size_t)e * 8192 + 4);
        float bb[8];
        bb[0] = fmaxf(q0.x, 0.f); bb[1] = fmaxf(q0.y, 0.f);
        bb[2] = fmaxf(q0.z, 0.f); bb[3] = fmaxf(q0.w, 0.f);
        bb[4] = fmaxf(q1.x, 0.f); bb[5] = fmaxf(q1.y, 0.f);
        bb[6] = fmaxf(q1.z, 0.f); bb[7] = fmaxf(q1.w, 0.f);
        float a[8];
#pragma unroll
        for (int i = 0; i < 8; ++i) a[i] = svkT[e * QSTR + tr + 16 * i];
        const float w = svkT[e * QSTR + 128];
#pragma unroll
        for (int i = 0; i < 8; ++i)
#pragma unroll
            for (int j = 0; j < 8; ++j)
                acc[i][j] = fmaf(a[i], bb[j], acc[i][j]);
#pragma unroll
        for (int j = 0; j < 8; ++j) den[j] = fmaf(w, bb[j], den[j]);
    }

    float rden[8];
#pragma unroll
    for (int j = 0; j < 8; ++j) rden[j] = 1.f / den[j];

#pragma unroll
    for (int i = 0; i < 8; ++i) {
        const int d = tr + 16 * i;
        float* op = out + (((size_t)b * 128 + d) * 8 + h) * 8192 + nbase + tc * 8;
        float4 o0, o1;
        o0.x = acc[i][0] * rden[0]; o0.y = acc[i][1] * rden[1];
        o0.z = acc[i][2] * rden[2]; o0.w = acc[i][3] * rden[3];
        o1.x = acc[i][4] * rden[4]; o1.y = acc[i][5] * rden[5];
        o1.z = acc[i][6] * rden[6]; o1.w = acc[i][7] * rden[7];
        *(float4*)op = o0;
        *(float4*)(op + 4) = o1;
    }
}

extern "C" void kernel_launch(void* const* d_in, const int* in_sizes, int n_in,
                              void* d_out, int out_size, void* d_ws, size_t ws_size,
                              hipStream_t stream)
{
    const float* q = (const float*)d_in[0];
    const float* k = (const float*)d_in[1];
    const float* v = (const float*)d_in[2];
    float* out = (float*)d_out;
    float* ws  = (float*)d_ws;

    const size_t vk_elems = 32ull * 129 * 128;   // 528384 floats = 2.11 MB

    int nsplit = 16;
    while (nsplit > 1 && (vk_elems * (size_t)(nsplit + 1)) * 4 > ws_size) nsplit >>= 1;
    const int chunk = 8192 / nsplit;

    float* partial = ws;
    float* vkbuf   = ws + vk_elems * (size_t)nsplit;

    dim3 g1(nsplit, 32);
    p1_vk_partial<<<g1, 256, 0, stream>>>(k, v, partial, nsplit, chunk);

    const int redn = (int)((vk_elems + 255) / 256);
    p2_vk_reduce<<<redn, 256, 0, stream>>>(partial, vkbuf, nsplit);

    dim3 g3(32, 32);
    p3_out<<<g3, 512, 67584 /* 128*132*4 dynamic LDS */, stream>>>(q, vkbuf, out);
}

// Round 3
// 182.328 us; speedup vs baseline: 3.8674x; 1.7876x over previous
//
#include <hip/hip_runtime.h>

// ---------------------------------------------------------------------------
// relu linear attention, bf16-MFMA version
//   q,k,v: [B=4][H=8][128][8192] fp32   out: [B][128][H][8192] fp32
//   p1: partial[bh][split][129][128] = sum_n v[d][n]*relu(k[e][n])  (bf16 MFMA)
//   p2: reduce -> vk fp32 -> split to vk_hi/vk_lo bf16 (+ den row fp32)
//   p3: out[d][n] = (sum_e (vk_hi+vk_lo)[d][e]*relu(q)[e][n]) / den[n]
// ---------------------------------------------------------------------------

typedef __attribute__((ext_vector_type(8))) short short8;
typedef __attribute__((ext_vector_type(4))) float f32x4;

__device__ inline unsigned short f2bf(float f) {
    unsigned u = __float_as_uint(f);
    u += 0x7FFFu + ((u >> 16) & 1u);            // RNE
    return (unsigned short)(u >> 16);
}
__device__ inline float bf2f(unsigned short h) {
    return __uint_as_float(((unsigned)h) << 16);
}
__device__ inline unsigned pk2(float a, float b) {
    return (unsigned)f2bf(a) | ((unsigned)f2bf(b) << 16);
}

// ============================ pass 1 =======================================
// block: 256 thr (4 waves, 2x2 wave grid), out tile 128d x 128e, K-chunk
// LDS: sA(v) [128][64]bf16 swizzled, sB(k+) same, + 8KB ksum-reduce scratch
__global__ __launch_bounds__(256, 3) void p1_vk(
    const float* __restrict__ K, const float* __restrict__ V,
    float* __restrict__ partial, int nsplit, int chunk)
{
    __shared__ char smem[40960];
    const int bh = blockIdx.y, split = blockIdx.x;
    const int t = threadIdx.x;
    const int lane = t & 63, w = t >> 6;
    const int dh = (w >> 1) << 6, eh = (w & 1) << 6;
    const int l15 = lane & 15, l4 = lane >> 4;
    const size_t base = (size_t)bh * (128 * 8192);
    const int n0 = split * chunk;
    const int srow = t >> 4;            // staging base row 0..15
    const int scol = (t & 15) << 2;     // staging fp32 col 0..60

    f32x4 acc[4][4];
#pragma unroll
    for (int i = 0; i < 4; ++i)
#pragma unroll
        for (int j = 0; j < 4; ++j)
            acc[i][j] = (f32x4){0.f, 0.f, 0.f, 0.f};
    float kpart[8] = {0.f, 0.f, 0.f, 0.f, 0.f, 0.f, 0.f, 0.f};

    for (int nt = n0; nt < n0 + chunk; nt += 64) {
        // ---- stage: fp32 -> bf16 into swizzled LDS ----
#pragma unroll
        for (int l = 0; l < 8; ++l) {
            const int row = srow + (l << 4);
            const float4 vv = *(const float4*)(V + base + (size_t)row * 8192 + nt + scol);
            float4 kk = *(const float4*)(K + base + (size_t)row * 8192 + nt + scol);
            kk.x = fmaxf(kk.x, 0.f); kk.y = fmaxf(kk.y, 0.f);
            kk.z = fmaxf(kk.z, 0.f); kk.w = fmaxf(kk.w, 0.f);
            kpart[l] += (kk.x + kk.y) + (kk.z + kk.w);
            const int off = (row * 128 + scol * 2) ^ ((row & 7) << 4);
            *(uint2*)(smem + off)         = make_uint2(pk2(vv.x, vv.y), pk2(vv.z, vv.w));
            *(uint2*)(smem + 16384 + off) = make_uint2(pk2(kk.x, kk.y), pk2(kk.z, kk.w));
        }
        __syncthreads();
        // ---- MFMA: 2 K-sub-steps of 32 ----
#pragma unroll
        for (int ks = 0; ks < 2; ++ks) {
            short8 Bf[4];
#pragma unroll
            for (int j = 0; j < 4; ++j) {
                const int er = eh + (j << 4) + l15;
                Bf[j] = *(const short8*)(smem + 16384 +
                        ((er * 128 + ks * 64 + l4 * 16) ^ ((er & 7) << 4)));
            }
#pragma unroll
            for (int i = 0; i < 4; ++i) {
                const int dr = dh + (i << 4) + l15;
                const short8 Af = *(const short8*)(smem +
                        ((dr * 128 + ks * 64 + l4 * 16) ^ ((dr & 7) << 4)));
#pragma unroll
                for (int j = 0; j < 4; ++j)
                    acc[i][j] = __builtin_amdgcn_mfma_f32_16x16x32_bf16(Af, Bf[j], acc[i][j], 0, 0, 0);
            }
        }
        __syncthreads();
    }

    // ---- ksum (den row) reduce via LDS ----
    float* krd = (float*)(smem + 32768);
#pragma unroll
    for (int l = 0; l < 8; ++l)
        krd[(srow + (l << 4)) * 16 + (t & 15)] = kpart[l];
    __syncthreads();

    float* p = partial + (size_t)(bh * nsplit + split) * (129 * 128);
#pragma unroll
    for (int i = 0; i < 4; ++i)
#pragma unroll
        for (int j = 0; j < 4; ++j)
#pragma unroll
            for (int jj = 0; jj < 4; ++jj)
                p[(dh + (i << 4) + (l4 << 2) + jj) * 128 + eh + (j << 4) + l15] = acc[i][j][jj];
    if (t < 128) {
        float s = 0.f;
#pragma unroll
        for (int m = 0; m < 16; ++m) s += krd[t * 16 + m];
        p[128 * 128 + t] = s;
    }
}

// ============================ pass 2 =======================================
// reduce partials; emit vk_hi/vk_lo bf16 in [bh][ek(4)][d(128)][e(32)] layout
__global__ __launch_bounds__(256) void p2_reduce(
    const float* __restrict__ partial, unsigned short* __restrict__ vkhi,
    unsigned short* __restrict__ vklo, float* __restrict__ vkden, int nsplit)
{
    const int t = blockIdx.x * 256 + threadIdx.x;
    if (t >= 32 * 129 * 128) return;
    const int bh = t / 16512, rc = t % 16512;
    const int d = rc >> 7, e = rc & 127;
    float s = 0.f;
    for (int i = 0; i < nsplit; ++i)
        s += partial[(size_t)(bh * nsplit + i) * 16512 + rc];
    if (d < 128) {
        const size_t off = (size_t)bh * 16384 + (e >> 5) * 4096 + d * 32 + (e & 31);
        const unsigned short h = f2bf(s);
        vkhi[off] = h;
        vklo[off] = f2bf(s - bf2f(h));
    } else {
        vkden[bh * 128 + e] = s;
    }
}

// ============================ pass 3 =======================================
// block: 256 thr (4 waves), out tile 128d x 256n, K = 128 e in 4 steps of 32
// LDS: vk slab hi/lo [128][40]bf16 (10240B ea), sQ [256][40]bf16 (20480B),
//      den [256]f32, vkden [128]f32  -> 42496 B total
#define VKH 0
#define VKL 10240
#define SQO 20480
#define DEN 40960
#define VKD 41984
__global__ __launch_bounds__(256, 2) void p3_out(
    const float* __restrict__ Q, const unsigned short* __restrict__ vkhi,
    const unsigned short* __restrict__ vklo, const float* __restrict__ vkden,
    float* __restrict__ out)
{
    __shared__ char smem[42496];
    const int bh = blockIdx.y;
    const int b = bh >> 3, h = bh & 7;
    const int n0 = blockIdx.x << 8;
    const int t = threadIdx.x;
    const int lane = t & 63, w = t >> 6;
    const int l15 = lane & 15, l4 = lane >> 4;
    const int wn = w << 6;

    if (t < 128) ((float*)(smem + VKD))[t] = vkden[bh * 128 + t];
    __syncthreads();

    const float* qb = Q + (size_t)bh * (128 * 8192) + n0 + t;   // this thread's n column
    const float* vkd = (const float*)(smem + VKD);
    const unsigned short* ghb = vkhi + (size_t)bh * 16384;
    const unsigned short* glb = vklo + (size_t)bh * 16384;

    f32x4 acc[8][4];
#pragma unroll
    for (int i = 0; i < 8; ++i)
#pragma unroll
        for (int j = 0; j < 4; ++j)
            acc[i][j] = (f32x4){0.f, 0.f, 0.f, 0.f};
    float den = 0.f;

    for (int ek = 0; ek < 4; ++ek) {
        const int e0 = ek << 5;
        // ---- stage vk slab (hi+lo): contiguous 8KB each ----
#pragma unroll
        for (int l = 0; l < 2; ++l) {
            const int s = t + (l << 8);         // 0..511
            const int d = s >> 2, c = s & 3;
            const int loff = d * 80 + c * 16;
            *(uint4*)(smem + VKH + loff) = *(const uint4*)(ghb + ek * 4096 + s * 8);
            *(uint4*)(smem + VKL + loff) = *(const uint4*)(glb + ek * 4096 + s * 8);
        }
        // ---- stage q transposed: thread owns one n column ----
#pragma unroll
        for (int sub = 0; sub < 4; ++sub) {
            const int j0 = e0 + (sub << 3);
            float vq[8];
#pragma unroll
            for (int m = 0; m < 8; ++m) vq[m] = qb[(size_t)(j0 + m) * 8192];
#pragma unroll
            for (int m = 0; m < 8; ++m) {
                vq[m] = fmaxf(vq[m], 0.f);
                den = fmaf(vkd[j0 + m], vq[m], den);
            }
            uint4 pq;
            pq.x = pk2(vq[0], vq[1]); pq.y = pk2(vq[2], vq[3]);
            pq.z = pk2(vq[4], vq[5]); pq.w = pk2(vq[6], vq[7]);
            *(uint4*)(smem + SQO + t * 80 + (sub << 4)) = pq;
        }
        __syncthreads();
        // ---- MFMA ----
        short8 Bf[4];
#pragma unroll
        for (int fn = 0; fn < 4; ++fn) {
            const int nr = wn + (fn << 4) + l15;
            Bf[fn] = *(const short8*)(smem + SQO + nr * 80 + l4 * 16);
        }
#pragma unroll
        for (int fd = 0; fd < 8; ++fd) {
            const int dr = (fd << 4) + l15;
            const short8 Ah = *(const short8*)(smem + VKH + dr * 80 + l4 * 16);
            const short8 Al = *(const short8*)(smem + VKL + dr * 80 + l4 * 16);
#pragma unroll
            for (int fn = 0; fn < 4; ++fn) {
                acc[fd][fn] = __builtin_amdgcn_mfma_f32_16x16x32_bf16(Ah, Bf[fn], acc[fd][fn], 0, 0, 0);
                acc[fd][fn] = __builtin_amdgcn_mfma_f32_16x16x32_bf16(Al, Bf[fn], acc[fd][fn], 0, 0, 0);
            }
        }
        __syncthreads();
    }

    // ---- normalize + store ----
    ((float*)(smem + DEN))[t] = den;
    __syncthreads();
    float rden[4];
#pragma unroll
    for (int fn = 0; fn < 4; ++fn)
        rden[fn] = 1.f / ((const float*)(smem + DEN))[wn + (fn << 4) + l15];

#pragma unroll
    for (int fd = 0; fd < 8; ++fd) {
#pragma unroll
        for (int fn = 0; fn < 4; ++fn) {
            const int n = n0 + wn + (fn << 4) + l15;
#pragma unroll
            for (int jj = 0; jj < 4; ++jj) {
                const int d = (fd << 4) + (l4 << 2) + jj;
                out[(((size_t)b * 128 + d) * 8 + h) * 8192 + n] = acc[fd][fn][jj] * rden[fn];
            }
        }
    }
}

// ============================ launch =======================================
extern "C" void kernel_launch(void* const* d_in, const int* in_sizes, int n_in,
                              void* d_out, int out_size, void* d_ws, size_t ws_size,
                              hipStream_t stream)
{
    const float* q = (const float*)d_in[0];
    const float* k = (const float*)d_in[1];
    const float* v = (const float*)d_in[2];
    float* out = (float*)d_out;
    char* ws = (char*)d_ws;

    int nsplit = 16;
    while (nsplit > 1 &&
           ((size_t)32 * nsplit * 16512 * 4 + (size_t)32 * 16384 * 2 * 2 + 32 * 128 * 4) > ws_size)
        nsplit >>= 1;
    const int chunk = 8192 / nsplit;

    float* partial = (float*)ws;
    unsigned short* vkhi = (unsigned short*)(ws + (size_t)32 * nsplit * 16512 * 4);
    unsigned short* vklo = vkhi + 32 * 16384;
    float* vkden = (float*)(vklo + 32 * 16384);

    p1_vk<<<dim3(nsplit, 32), 256, 0, stream>>>(k, v, partial, nsplit, chunk);
    p2_reduce<<<(32 * 129 * 128 + 255) / 256, 256, 0, stream>>>(partial, vkhi, vklo, vkden, nsplit);
    p3_out<<<dim3(32, 32), 256, 0, stream>>>(q, vkhi, vklo, vkden, out);
}

// Round 4
// 182.079 us; speedup vs baseline: 3.8726x; 1.0014x over previous
//
#include <hip/hip_runtime.h>

// ---------------------------------------------------------------------------
// relu linear attention, bf16-MFMA, pipelined p1
//   q,k,v: [B=4][H=8][128][8192] fp32   out: [B][128][H][8192] fp32
//   p1: partial[bh][split][129][128] = sum_n v[d][n]*relu(k[e][n])  (bf16 MFMA,
//       double-buffered LDS + register prefetch, 32-n tiles)
//   p2: reduce -> vk fp32 -> split to vk_hi/vk_lo bf16 (+ den row fp32)
//   p3: out[d][n] = (sum_e (vk_hi+vk_lo)[d][e]*relu(q)[e][n]) / den[n]
// ---------------------------------------------------------------------------

typedef __attribute__((ext_vector_type(8))) short short8;
typedef __attribute__((ext_vector_type(4))) float f32x4;

__device__ inline unsigned short f2bf(float f) {
    unsigned u = __float_as_uint(f);
    u += 0x7FFFu + ((u >> 16) & 1u);            // RNE
    return (unsigned short)(u >> 16);
}
__device__ inline float bf2f(unsigned short h) {
    return __uint_as_float(((unsigned)h) << 16);
}
__device__ inline unsigned pk2(float a, float b) {
    return (unsigned)f2bf(a) | ((unsigned)f2bf(b) << 16);
}
__device__ inline uint4 pack8(float4 a, float4 b) {
    return make_uint4(pk2(a.x, a.y), pk2(a.z, a.w), pk2(b.x, b.y), pk2(b.z, b.w));
}
__device__ inline float4 relu4s(float4 x, float& s) {
    x.x = fmaxf(x.x, 0.f); x.y = fmaxf(x.y, 0.f);
    x.z = fmaxf(x.z, 0.f); x.w = fmaxf(x.w, 0.f);
    s += (x.x + x.y) + (x.z + x.w);
    return x;
}

// ============================ pass 1 =======================================
// 256 thr (2x2 waves), out tile 128d x 128e; 32-n K-tiles, double-buffered.
// LDS map (bytes): buf*16384 + {V:0, K:8192} + swizzled(row*64 + col16*16)
//   swizzle: addr ^ ((row&7)<<4)  (bijective; 2-way max on b128 read/write)
__device__ __forceinline__ void p1_mfma_step(const char* smem, int bufbase,
        int dh, int eh, int l15, int l4, f32x4 acc[4][4])
{
    short8 Bf[4];
#pragma unroll
    for (int j = 0; j < 4; ++j) {
        const int er = eh + (j << 4) + l15;
        Bf[j] = *(const short8*)(smem + bufbase + 8192 +
                ((er * 64 + l4 * 16) ^ ((er & 7) << 4)));
    }
#pragma unroll
    for (int i = 0; i < 4; ++i) {
        const int dr = dh + (i << 4) + l15;
        const short8 Af = *(const short8*)(smem + bufbase +
                ((dr * 64 + l4 * 16) ^ ((dr & 7) << 4)));
#pragma unroll
        for (int j = 0; j < 4; ++j)
            acc[i][j] = __builtin_amdgcn_mfma_f32_16x16x32_bf16(Af, Bf[j], acc[i][j], 0, 0, 0);
    }
}

__global__ __launch_bounds__(256, 3) void p1_vk(
    const float* __restrict__ K, const float* __restrict__ V,
    float* __restrict__ partial, int nsplit, int chunk)
{
    __shared__ uint4 smem4[2048];              // 32 KB
    char* smem = (char*)smem4;
    const int bh = blockIdx.y, split = blockIdx.x;
    const int t = threadIdx.x;
    const int lane = t & 63, w = t >> 6;
    const int dh = (w >> 1) << 6, eh = (w & 1) << 6;
    const int l15 = lane & 15, l4 = lane >> 4;
    const size_t base = (size_t)bh * (128 * 8192);
    const int n0 = split * chunk;
    const int r0 = t >> 2;                     // staging row 0..63 (and +64)
    const int c0 = (t & 3) << 3;               // staging n-offset 0,8,16,24
    const size_t H64 = (size_t)64 * 8192;
    const int woff = (r0 * 64 + (t & 3) * 16) ^ ((r0 & 7) << 4);

    const float* Vb = V + base + (size_t)r0 * 8192 + c0;
    const float* Kb = K + base + (size_t)r0 * 8192 + c0;

    f32x4 acc[4][4];
#pragma unroll
    for (int i = 0; i < 4; ++i)
#pragma unroll
        for (int j = 0; j < 4; ++j)
            acc[i][j] = (f32x4){0.f, 0.f, 0.f, 0.f};
    float kp0 = 0.f, kp1 = 0.f;

    const int niter = chunk >> 5;

    // ---- prologue: stage tile 0 into buf 0 ----
    {
        const size_t nt = n0;
        float4 va0 = *(const float4*)(Vb + nt);
        float4 va1 = *(const float4*)(Vb + nt + 4);
        float4 vb0 = *(const float4*)(Vb + H64 + nt);
        float4 vb1 = *(const float4*)(Vb + H64 + nt + 4);
        float4 ka0 = *(const float4*)(Kb + nt);
        float4 ka1 = *(const float4*)(Kb + nt + 4);
        float4 kb0 = *(const float4*)(Kb + H64 + nt);
        float4 kb1 = *(const float4*)(Kb + H64 + nt + 4);
        ka0 = relu4s(ka0, kp0); ka1 = relu4s(ka1, kp0);
        kb0 = relu4s(kb0, kp1); kb1 = relu4s(kb1, kp1);
        *(uint4*)(smem + woff)              = pack8(va0, va1);
        *(uint4*)(smem + woff + 4096)       = pack8(vb0, vb1);
        *(uint4*)(smem + 8192 + woff)        = pack8(ka0, ka1);
        *(uint4*)(smem + 8192 + woff + 4096) = pack8(kb0, kb1);
    }
    __syncthreads();

    int cur = 0;
    for (int it = 1; it < niter; ++it) {
        const size_t nt = n0 + (it << 5);
        // ---- issue next tile's loads (overlap with MFMA below) ----
        float4 va0 = *(const float4*)(Vb + nt);
        float4 va1 = *(const float4*)(Vb + nt + 4);
        float4 vb0 = *(const float4*)(Vb + H64 + nt);
        float4 vb1 = *(const float4*)(Vb + H64 + nt + 4);
        float4 ka0 = *(const float4*)(Kb + nt);
        float4 ka1 = *(const float4*)(Kb + nt + 4);
        float4 kb0 = *(const float4*)(Kb + H64 + nt);
        float4 kb1 = *(const float4*)(Kb + H64 + nt + 4);
        // ---- consume current buffer ----
        p1_mfma_step(smem, cur * 16384, dh, eh, l15, l4, acc);
        // ---- pack into other buffer ----
        ka0 = relu4s(ka0, kp0); ka1 = relu4s(ka1, kp0);
        kb0 = relu4s(kb0, kp1); kb1 = relu4s(kb1, kp1);
        const int nb = (cur ^ 1) * 16384;
        *(uint4*)(smem + nb + woff)              = pack8(va0, va1);
        *(uint4*)(smem + nb + woff + 4096)       = pack8(vb0, vb1);
        *(uint4*)(smem + nb + 8192 + woff)        = pack8(ka0, ka1);
        *(uint4*)(smem + nb + 8192 + woff + 4096) = pack8(kb0, kb1);
        __syncthreads();
        cur ^= 1;
    }
    p1_mfma_step(smem, cur * 16384, dh, eh, l15, l4, acc);
    __syncthreads();

    // ---- den-row (sum_n relu(k)) reduce via 2KB LDS overlay ----
    float* krd = (float*)smem;
    krd[r0 * 4 + (t & 3)] = kp0;
    krd[(r0 + 64) * 4 + (t & 3)] = kp1;
    __syncthreads();

    float* p = partial + (size_t)(bh * nsplit + split) * (129 * 128);
#pragma unroll
    for (int i = 0; i < 4; ++i)
#pragma unroll
        for (int j = 0; j < 4; ++j)
#pragma unroll
            for (int jj = 0; jj < 4; ++jj)
                p[(dh + (i << 4) + (l4 << 2) + jj) * 128 + eh + (j << 4) + l15] = acc[i][j][jj];
    if (t < 128) {
        float s = krd[t * 4] + krd[t * 4 + 1] + krd[t * 4 + 2] + krd[t * 4 + 3];
        p[128 * 128 + t] = s;
    }
}

// ============================ pass 2 =======================================
__global__ __launch_bounds__(256) void p2_reduce(
    const float* __restrict__ partial, unsigned short* __restrict__ vkhi,
    unsigned short* __restrict__ vklo, float* __restrict__ vkden, int nsplit)
{
    const int t = blockIdx.x * 256 + threadIdx.x;
    if (t >= 32 * 129 * 128) return;
    const int bh = t / 16512, rc = t % 16512;
    const int d = rc >> 7, e = rc & 127;
    float s = 0.f;
    for (int i = 0; i < nsplit; ++i)
        s += partial[(size_t)(bh * nsplit + i) * 16512 + rc];
    if (d < 128) {
        const size_t off = (size_t)bh * 16384 + (e >> 5) * 4096 + d * 32 + (e & 31);
        const unsigned short h = f2bf(s);
        vkhi[off] = h;
        vklo[off] = f2bf(s - bf2f(h));
    } else {
        vkden[bh * 128 + e] = s;
    }
}

// ============================ pass 3 =======================================
#define VKH 0
#define VKL 10240
#define SQO 20480
#define DEN 40960
#define VKD 41984
__global__ __launch_bounds__(256, 2) void p3_out(
    const float* __restrict__ Q, const unsigned short* __restrict__ vkhi,
    const unsigned short* __restrict__ vklo, const float* __restrict__ vkden,
    float* __restrict__ out)
{
    __shared__ char smem[42496];
    const int bh = blockIdx.y;
    const int b = bh >> 3, h = bh & 7;
    const int n0 = blockIdx.x << 8;
    const int t = threadIdx.x;
    const int lane = t & 63, w = t >> 6;
    const int l15 = lane & 15, l4 = lane >> 4;
    const int wn = w << 6;

    if (t < 128) ((float*)(smem + VKD))[t] = vkden[bh * 128 + t];
    __syncthreads();

    const float* qb = Q + (size_t)bh * (128 * 8192) + n0 + t;   // this thread's n column
    const float* vkd = (const float*)(smem + VKD);
    const unsigned short* ghb = vkhi + (size_t)bh * 16384;
    const unsigned short* glb = vklo + (size_t)bh * 16384;

    f32x4 acc[8][4];
#pragma unroll
    for (int i = 0; i < 8; ++i)
#pragma unroll
        for (int j = 0; j < 4; ++j)
            acc[i][j] = (f32x4){0.f, 0.f, 0.f, 0.f};
    float den = 0.f;

    for (int ek = 0; ek < 4; ++ek) {
        const int e0 = ek << 5;
#pragma unroll
        for (int l = 0; l < 2; ++l) {
            const int s = t + (l << 8);
            const int d = s >> 2, c = s & 3;
            const int loff = d * 80 + c * 16;
            *(uint4*)(smem + VKH + loff) = *(const uint4*)(ghb + ek * 4096 + s * 8);
            *(uint4*)(smem + VKL + loff) = *(const uint4*)(glb + ek * 4096 + s * 8);
        }
#pragma unroll
        for (int sub = 0; sub < 4; ++sub) {
            const int j0 = e0 + (sub << 3);
            float vq[8];
#pragma unroll
            for (int m = 0; m < 8; ++m) vq[m] = qb[(size_t)(j0 + m) * 8192];
#pragma unroll
            for (int m = 0; m < 8; ++m) {
                vq[m] = fmaxf(vq[m], 0.f);
                den = fmaf(vkd[j0 + m], vq[m], den);
            }
            uint4 pq;
            pq.x = pk2(vq[0], vq[1]); pq.y = pk2(vq[2], vq[3]);
            pq.z = pk2(vq[4], vq[5]); pq.w = pk2(vq[6], vq[7]);
            *(uint4*)(smem + SQO + t * 80 + (sub << 4)) = pq;
        }
        __syncthreads();
        short8 Bf[4];
#pragma unroll
        for (int fn = 0; fn < 4; ++fn) {
            const int nr = wn + (fn << 4) + l15;
            Bf[fn] = *(const short8*)(smem + SQO + nr * 80 + l4 * 16);
        }
#pragma unroll
        for (int fd = 0; fd < 8; ++fd) {
            const int dr = (fd << 4) + l15;
            const short8 Ah = *(const short8*)(smem + VKH + dr * 80 + l4 * 16);
            const short8 Al = *(const short8*)(smem + VKL + dr * 80 + l4 * 16);
#pragma unroll
            for (int fn = 0; fn < 4; ++fn) {
                acc[fd][fn] = __builtin_amdgcn_mfma_f32_16x16x32_bf16(Ah, Bf[fn], acc[fd][fn], 0, 0, 0);
                acc[fd][fn] = __builtin_amdgcn_mfma_f32_16x16x32_bf16(Al, Bf[fn], acc[fd][fn], 0, 0, 0);
            }
        }
        __syncthreads();
    }

    ((float*)(smem + DEN))[t] = den;
    __syncthreads();
    float rden[4];
#pragma unroll
    for (int fn = 0; fn < 4; ++fn)
        rden[fn] = 1.f / ((const float*)(smem + DEN))[wn + (fn << 4) + l15];

#pragma unroll
    for (int fd = 0; fd < 8; ++fd) {
#pragma unroll
        for (int fn = 0; fn < 4; ++fn) {
            const int n = n0 + wn + (fn << 4) + l15;
#pragma unroll
            for (int jj = 0; jj < 4; ++jj) {
                const int d = (fd << 4) + (l4 << 2) + jj;
                out[(((size_t)b * 128 + d) * 8 + h) * 8192 + n] = acc[fd][fn][jj] * rden[fn];
            }
        }
    }
}

// ============================ launch =======================================
extern "C" void kernel_launch(void* const* d_in, const int* in_sizes, int n_in,
                              void* d_out, int out_size, void* d_ws, size_t ws_size,
                              hipStream_t stream)
{
    const float* q = (const float*)d_in[0];
    const float* k = (const float*)d_in[1];
    const float* v = (const float*)d_in[2];
    float* out = (float*)d_out;
    char* ws = (char*)d_ws;

    int nsplit = 32;
    while (nsplit > 1 &&
           ((size_t)32 * nsplit * 16512 * 4 + (size_t)32 * 16384 * 2 * 2 + 32 * 128 * 4) > ws_size)
        nsplit >>= 1;
    const int chunk = 8192 / nsplit;

    float* partial = (float*)ws;
    unsigned short* vkhi = (unsigned short*)(ws + (size_t)32 * nsplit * 16512 * 4);
    unsigned short* vklo = vkhi + 32 * 16384;
    float* vkden = (float*)(vklo + 32 * 16384);

    p1_vk<<<dim3(nsplit, 32), 256, 0, stream>>>(k, v, partial, nsplit, chunk);
    p2_reduce<<<(32 * 129 * 128 + 255) / 256, 256, 0, stream>>>(partial, vkhi, vklo, vkden, nsplit);
    p3_out<<<dim3(32, 32), 256, 0, stream>>>(q, vkhi, vklo, vkden, out);
}

// Round 5
// 160.519 us; speedup vs baseline: 4.3928x; 1.1343x over previous
//
#include <hip/hip_runtime.h>

// ---------------------------------------------------------------------------
// relu linear attention, bf16-MFMA
//   q,k,v: [B=4][H=8][128][8192] fp32   out: [B][128][H][8192] fp32
//   p1: partial[bh][split][129][128] = sum_n v[d][n]*relu(k[e][n])
//       (bf16 MFMA; TN=64 tiles, contiguous staging reads, double-buffered
//        LDS + depth-1 register prefetch, 1 barrier/tile)
//   p2: reduce -> vk fp32 -> split to vk_hi/vk_lo bf16 (+ den row fp32)
//   p3: out[d][n] = (sum_e (vk_hi+vk_lo)[d][e]*relu(q)[e][n]) / den[n]
// ---------------------------------------------------------------------------

typedef __attribute__((ext_vector_type(8))) short short8;
typedef __attribute__((ext_vector_type(4))) float f32x4;

__device__ inline unsigned short f2bf(float f) {
    unsigned u = __float_as_uint(f);
    u += 0x7FFFu + ((u >> 16) & 1u);            // RNE
    return (unsigned short)(u >> 16);
}
__device__ inline float bf2f(unsigned short h) {
    return __uint_as_float(((unsigned)h) << 16);
}
__device__ inline unsigned pk2(float a, float b) {
    return (unsigned)f2bf(a) | ((unsigned)f2bf(b) << 16);
}

// ============================ pass 1 =======================================
// 256 thr (2x2 waves), out tile 128d x 128e; TN=64-n tiles.
// LDS: buf*32768 + {V:0, K:16384}; bf16 row = 128 B; swizzle byte ^ ((row&7)<<4)
__global__ __launch_bounds__(256, 2) void p1_vk(
    const float* __restrict__ K, const float* __restrict__ V,
    float* __restrict__ partial, int nsplit, int chunk)
{
    __shared__ char smem[65536];
    const int bh = blockIdx.y, split = blockIdx.x;
    const int t = threadIdx.x;
    const int lane = t & 63, w = t >> 6;
    const int dh = (w >> 1) << 6, eh = (w & 1) << 6;
    const int l15 = lane & 15, l4 = lane >> 4;
    const size_t base = (size_t)bh * (128 * 8192);
    const int n0 = split * chunk;
    const int rq = t >> 4;                       // 0..15
    const int cq = t & 15;                       // float4 col 0..15
    const int cw = (cq * 8) ^ ((rq & 7) << 4);   // swizzled byte col (writes)

    const float* Vb = V + base + (size_t)rq * 8192 + cq * 4 + n0;
    const float* Kb = K + base + (size_t)rq * 8192 + cq * 4 + n0;

    f32x4 acc[4][4];
#pragma unroll
    for (int i = 0; i < 4; ++i)
#pragma unroll
        for (int j = 0; j < 4; ++j)
            acc[i][j] = (f32x4){0.f, 0.f, 0.f, 0.f};
    float kp[8] = {0.f, 0.f, 0.f, 0.f, 0.f, 0.f, 0.f, 0.f};

    const int niter = chunk >> 6;
    float4 lv[8], lk[8];

    auto loadT = [&](int nt) {
#pragma unroll
        for (int i = 0; i < 8; ++i) {
            lv[i] = *(const float4*)(Vb + (size_t)(i << 4) * 8192 + nt);
            lk[i] = *(const float4*)(Kb + (size_t)(i << 4) * 8192 + nt);
        }
    };
    auto packT = [&](int bufidx) {
        char* bV = smem + (bufidx << 15);
        char* bK = bV + 16384;
#pragma unroll
        for (int i = 0; i < 8; ++i) {
            const int row = (i << 4) + rq;
            *(uint2*)(bV + row * 128 + cw) =
                make_uint2(pk2(lv[i].x, lv[i].y), pk2(lv[i].z, lv[i].w));
            float4 kk = lk[i];
            kk.x = fmaxf(kk.x, 0.f); kk.y = fmaxf(kk.y, 0.f);
            kk.z = fmaxf(kk.z, 0.f); kk.w = fmaxf(kk.w, 0.f);
            kp[i] += (kk.x + kk.y) + (kk.z + kk.w);
            *(uint2*)(bK + row * 128 + cw) =
                make_uint2(pk2(kk.x, kk.y), pk2(kk.z, kk.w));
        }
    };
    auto computeT = [&](int bufidx) {
        const char* bV = smem + (bufidx << 15);
        const char* bK = bV + 16384;
#pragma unroll
        for (int sub = 0; sub < 2; ++sub) {
            short8 Bf[4];
#pragma unroll
            for (int j = 0; j < 4; ++j) {
                const int er = eh + (j << 4) + l15;
                Bf[j] = *(const short8*)(bK +
                        ((er * 128 + sub * 64 + l4 * 16) ^ ((er & 7) << 4)));
            }
#pragma unroll
            for (int i4 = 0; i4 < 4; ++i4) {
                const int dr = dh + (i4 << 4) + l15;
                const short8 Af = *(const short8*)(bV +
                        ((dr * 128 + sub * 64 + l4 * 16) ^ ((dr & 7) << 4)));
#pragma unroll
                for (int j = 0; j < 4; ++j)
                    acc[i4][j] = __builtin_amdgcn_mfma_f32_16x16x32_bf16(
                            Af, Bf[j], acc[i4][j], 0, 0, 0);
            }
        }
    };

    // prologue: tile 0 -> buf 0
    loadT(0);
    packT(0);
    __syncthreads();

    for (int it = 0; it < niter; ++it) {
        if (it + 1 < niter) loadT((it + 1) << 6);   // prefetch next tile
        computeT(it & 1);                            // consume current buffer
        if (it + 1 < niter) packT((it + 1) & 1);     // convert+write other buffer
        __syncthreads();
    }

    // den-row (sum_n relu(k)) reduce via LDS overlay
    float* krd = (float*)smem;
#pragma unroll
    for (int i = 0; i < 8; ++i)
        krd[((i << 4) + rq) * 16 + cq] = kp[i];
    __syncthreads();

    float* p = partial + (size_t)(bh * nsplit + split) * 16512;
#pragma unroll
    for (int i = 0; i < 4; ++i)
#pragma unroll
        for (int j = 0; j < 4; ++j)
#pragma unroll
            for (int jj = 0; jj < 4; ++jj)
                p[(dh + (i << 4) + (l4 << 2) + jj) * 128 + eh + (j << 4) + l15] = acc[i][j][jj];
    if (t < 128) {
        float s = 0.f;
#pragma unroll
        for (int m = 0; m < 16; ++m) s += krd[t * 16 + m];
        p[16384 + t] = s;
    }
}

// ============================ pass 2 =======================================
__global__ __launch_bounds__(256) void p2_reduce(
    const float* __restrict__ partial, unsigned short* __restrict__ vkhi,
    unsigned short* __restrict__ vklo, float* __restrict__ vkden, int nsplit)
{
    const int t = blockIdx.x * 256 + threadIdx.x;
    if (t >= 32 * 129 * 128) return;
    const int bh = t / 16512, rc = t % 16512;
    const int d = rc >> 7, e = rc & 127;
    float s = 0.f;
    for (int i = 0; i < nsplit; ++i)
        s += partial[(size_t)(bh * nsplit + i) * 16512 + rc];
    if (d < 128) {
        const size_t off = (size_t)bh * 16384 + (e >> 5) * 4096 + d * 32 + (e & 31);
        const unsigned short h = f2bf(s);
        vkhi[off] = h;
        vklo[off] = f2bf(s - bf2f(h));
    } else {
        vkden[bh * 128 + e] = s;
    }
}

// ============================ pass 3 =======================================
#define VKH 0
#define VKL 10240
#define SQO 20480
#define DEN 40960
#define VKD 41984
__global__ __launch_bounds__(256, 2) void p3_out(
    const float* __restrict__ Q, const unsigned short* __restrict__ vkhi,
    const unsigned short* __restrict__ vklo, const float* __restrict__ vkden,
    float* __restrict__ out)
{
    __shared__ char smem[42496];
    const int bh = blockIdx.y;
    const int b = bh >> 3, h = bh & 7;
    const int n0 = blockIdx.x << 8;
    const int t = threadIdx.x;
    const int lane = t & 63, w = t >> 6;
    const int l15 = lane & 15, l4 = lane >> 4;
    const int wn = w << 6;

    if (t < 128) ((float*)(smem + VKD))[t] = vkden[bh * 128 + t];
    __syncthreads();

    const float* qb = Q + (size_t)bh * (128 * 8192) + n0 + t;   // this thread's n column
    const float* vkd = (const float*)(smem + VKD);
    const unsigned short* ghb = vkhi + (size_t)bh * 16384;
    const unsigned short* glb = vklo + (size_t)bh * 16384;

    f32x4 acc[8][4];
#pragma unroll
    for (int i = 0; i < 8; ++i)
#pragma unroll
        for (int j = 0; j < 4; ++j)
            acc[i][j] = (f32x4){0.f, 0.f, 0.f, 0.f};
    float den = 0.f;

    for (int ek = 0; ek < 4; ++ek) {
        const int e0 = ek << 5;
#pragma unroll
        for (int l = 0; l < 2; ++l) {
            const int s = t + (l << 8);
            const int d = s >> 2, c = s & 3;
            const int loff = d * 80 + c * 16;
            *(uint4*)(smem + VKH + loff) = *(const uint4*)(ghb + ek * 4096 + s * 8);
            *(uint4*)(smem + VKL + loff) = *(const uint4*)(glb + ek * 4096 + s * 8);
        }
#pragma unroll
        for (int sub = 0; sub < 4; ++sub) {
            const int j0 = e0 + (sub << 3);
            float vq[8];
#pragma unroll
            for (int m = 0; m < 8; ++m) vq[m] = qb[(size_t)(j0 + m) * 8192];
#pragma unroll
            for (int m = 0; m < 8; ++m) {
                vq[m] = fmaxf(vq[m], 0.f);
                den = fmaf(vkd[j0 + m], vq[m], den);
            }
            uint4 pq;
            pq.x = pk2(vq[0], vq[1]); pq.y = pk2(vq[2], vq[3]);
            pq.z = pk2(vq[4], vq[5]); pq.w = pk2(vq[6], vq[7]);
            *(uint4*)(smem + SQO + t * 80 + (sub << 4)) = pq;
        }
        __syncthreads();
        short8 Bf[4];
#pragma unroll
        for (int fn = 0; fn < 4; ++fn) {
            const int nr = wn + (fn << 4) + l15;
            Bf[fn] = *(const short8*)(smem + SQO + nr * 80 + l4 * 16);
        }
#pragma unroll
        for (int fd = 0; fd < 8; ++fd) {
            const int dr = (fd << 4) + l15;
            const short8 Ah = *(const short8*)(smem + VKH + dr * 80 + l4 * 16);
            const short8 Al = *(const short8*)(smem + VKL + dr * 80 + l4 * 16);
#pragma unroll
            for (int fn = 0; fn < 4; ++fn) {
                acc[fd][fn] = __builtin_amdgcn_mfma_f32_16x16x32_bf16(Ah, Bf[fn], acc[fd][fn], 0, 0, 0);
                acc[fd][fn] = __builtin_amdgcn_mfma_f32_16x16x32_bf16(Al, Bf[fn], acc[fd][fn], 0, 0, 0);
            }
        }
        __syncthreads();
    }

    ((float*)(smem + DEN))[t] = den;
    __syncthreads();
    float rden[4];
#pragma unroll
    for (int fn = 0; fn < 4; ++fn)
        rden[fn] = 1.f / ((const float*)(smem + DEN))[wn + (fn << 4) + l15];

#pragma unroll
    for (int fd = 0; fd < 8; ++fd) {
#pragma unroll
        for (int fn = 0; fn < 4; ++fn) {
            const int n = n0 + wn + (fn << 4) + l15;
#pragma unroll
            for (int jj = 0; jj < 4; ++jj) {
                const int d = (fd << 4) + (l4 << 2) + jj;
                out[(((size_t)b * 128 + d) * 8 + h) * 8192 + n] = acc[fd][fn][jj] * rden[fn];
            }
        }
    }
}

// ============================ launch =======================================
extern "C" void kernel_launch(void* const* d_in, const int* in_sizes, int n_in,
                              void* d_out, int out_size, void* d_ws, size_t ws_size,
                              hipStream_t stream)
{
    const float* q = (const float*)d_in[0];
    const float* k = (const float*)d_in[1];
    const float* v = (const float*)d_in[2];
    float* out = (float*)d_out;
    char* ws = (char*)d_ws;

    int nsplit = 16;
    while (nsplit > 1 &&
           ((size_t)32 * nsplit * 16512 * 4 + (size_t)32 * 16384 * 2 * 2 + 32 * 128 * 4) > ws_size)
        nsplit >>= 1;
    const int chunk = 8192 / nsplit;

    float* partial = (float*)ws;
    unsigned short* vkhi = (unsigned short*)(ws + (size_t)32 * nsplit * 16512 * 4);
    unsigned short* vklo = vkhi + 32 * 16384;
    float* vkden = (float*)(vklo + 32 * 16384);

    p1_vk<<<dim3(nsplit, 32), 256, 0, stream>>>(k, v, partial, nsplit, chunk);
    p2_reduce<<<(32 * 129 * 128 + 255) / 256, 256, 0, stream>>>(partial, vkhi, vklo, vkden, nsplit);
    p3_out<<<dim3(32, 32), 256, 0, stream>>>(q, vkhi, vklo, vkden, out);
}